// Round 6
// baseline (1921.737 us; speedup 1.0000x reference)
//
#include <hip/hip_runtime.h>

#define BATCH 8192
#define NSTEP 29
#define BTILE 32
#define BT    1024         // 16 waves: 13 compute, 3 input-staging
#define XS    72           // x stride (bf16): [0,48)=tactile/out4, [48,54)=act, [54,60)=state, [60]=1
#define HS    232          // h1 stride: [0,200)=h, [208]=1
#define H2S   296          // h2cat stride: [0,200)=h2, [208,256)=inp, [256]=1
#define OS    232          // o3 stride: [0,200)=o3, [208]=1

// fragment-packed weights: each (tile,kc,gate) = 512 contiguous elems (lane*8+e)
#define OW1   0            // W1: [13][9][4][512]
#define OW2   239616       // W2: [13][14][4][512]
#define OF1   612352       // FC1: [13][9][512]
#define OF2   672256       // FC2: [3][7][512]
#define WTOT  683008

typedef __bf16 bf16x8 __attribute__((ext_vector_type(8)));
typedef float  f32x4  __attribute__((ext_vector_type(4)));

__device__ __forceinline__ unsigned short f2bf(float f) {
    union { float f; unsigned u; } v; v.f = f;
    unsigned r = v.u + 0x7fffu + ((v.u >> 16) & 1u);
    return (unsigned short)(r >> 16);
}
__device__ __forceinline__ float sigf(float x) { return 1.0f / (1.0f + __expf(-x)); }
__device__ __forceinline__ float tanh_(float x) {
    x = fminf(15.0f, fmaxf(-15.0f, x));
    float e = __expf(2.0f * x);
    return (e - 1.0f) / (e + 1.0f);
}

__device__ __forceinline__ void load1(bf16x8 &w, const unsigned short* p) {
    asm volatile("global_load_dwordx4 %0, %1, off" : "=&v"(w) : "v"(p));
}

// global per-wave load sequence, period 108: [P1 0..35][P2 36..91][P3 92..100][P4 101..107]
__device__ __forceinline__ const unsigned short* waddr(
    const unsigned short* tb1, const unsigned short* tb2,
    const unsigned short* tf1, const unsigned short* tf2, int i) {
    i %= 108;
    if (i < 36)  return tb1 + (i << 9);
    if (i < 92)  return tb2 + ((i - 36) << 9);
    if (i < 101) return tf1 + ((i - 92) << 9);
    return tf2 + ((i - 101) << 9);
}

#define WQI(i, src) do { load1(wq[(i) % 12], waddr(tb1, tb2, tf1, tf2, (src))); } while (0)
#define VMWAIT do { asm volatile("s_waitcnt vmcnt(11)"); __builtin_amdgcn_sched_barrier(0); } while (0)
#define PHASE_BARRIER do { asm volatile("s_waitcnt lgkmcnt(0)" ::: "memory"); __builtin_amdgcn_s_barrier(); } while (0)

// repack weights into per-wave fragment order (coalesced 1KB bursts), bias folded as K-col
__global__ void actp_prep(const float* __restrict__ wih1, const float* __restrict__ whh1,
                          const float* __restrict__ bih1, const float* __restrict__ bhh1,
                          const float* __restrict__ wih2, const float* __restrict__ whh2,
                          const float* __restrict__ bih2, const float* __restrict__ bhh2,
                          const float* __restrict__ fc1w, const float* __restrict__ fc1b,
                          const float* __restrict__ fc2w, const float* __restrict__ fc2b,
                          unsigned short* __restrict__ ws) {
    int i = blockIdx.x * 256 + threadIdx.x;
    if (i >= WTOT) return;
    float v = 0.f;
    if (i < OW2) {                               // W1 [13][9][4][512], K: x(64)|h1(224)
        int blk = i >> 9, le = i & 511;
        int lane = le >> 3, e = le & 7;
        int g = blk & 3, t2 = blk >> 2;
        int kc = t2 % 9, jt = t2 / 9;
        int n = jt * 16 + (lane & 15), k = kc * 32 + (lane >> 4) * 8 + e;
        if (n < 200) {
            int o = g * 200 + n;
            if (k < 60)                   v = wih1[o * 60 + k];
            else if (k == 60)             v = bih1[o] + bhh1[o];
            else if (k >= 64 && k < 264)  v = whh1[o * 200 + (k - 64)];
        }
    } else if (i < OF1) {                        // W2 [13][14][4][512], K: h1(224)|h2(224)
        int j = i - OW2;
        int blk = j >> 9, le = j & 511;
        int lane = le >> 3, e = le & 7;
        int g = blk & 3, t2 = blk >> 2;
        int kc = t2 % 14, jt = t2 / 14;
        int n = jt * 16 + (lane & 15), k = kc * 32 + (lane >> 4) * 8 + e;
        if (n < 200) {
            int o = g * 200 + n;
            if (k < 200)                   v = wih2[o * 200 + k];
            else if (k == 208)             v = bih2[o] + bhh2[o];
            else if (k >= 224 && k < 424)  v = whh2[o * 200 + (k - 224)];
        }
    } else if (i < OF2) {                        // FC1 [13][9][512]
        int j = i - OF1;
        int blk = j >> 9, le = j & 511;
        int lane = le >> 3, e = le & 7;
        int kc = blk % 9, jt = blk / 9;
        int n = jt * 16 + (lane & 15), k = kc * 32 + (lane >> 4) * 8 + e;
        if (n < 200) {
            if (k < 200)                   v = fc1w[n * 248 + k];
            else if (k >= 208 && k < 256)  v = fc1w[n * 248 + 200 + (k - 208)];
            else if (k == 256)             v = fc1b[n];
        }
    } else {                                     // FC2 [3][7][512]
        int j = i - OF2;
        int blk = j >> 9, le = j & 511;
        int lane = le >> 3, e = le & 7;
        int kc = blk % 7, nt = blk / 7;
        int n = nt * 16 + (lane & 15), k = kc * 32 + (lane >> 4) * 8 + e;
        if (k < 200)       v = fc2w[n * 200 + k];
        else if (k == 208) v = fc2b[n];
    }
    ws[i] = (v == 0.f) ? (unsigned short)0 : f2bf(v);
}

__global__ __launch_bounds__(BT, 4) void actp_main(
    const float* __restrict__ tact, const float* __restrict__ acts,
    const unsigned short* __restrict__ ws, float* __restrict__ out)
{
    __shared__ alignas(16) unsigned short xbuf[BTILE * XS];
    __shared__ alignas(16) unsigned short h1buf[2][BTILE * HS];
    __shared__ alignas(16) unsigned short h2cat[2][BTILE * H2S];
    __shared__ alignas(16) unsigned short o3buf[BTILE * OS];

    const int tid  = threadIdx.x;
    const int lane = tid & 63;
    const int wid  = tid >> 6;      // 0..15
    const int lrow = lane & 15;
    const int lgrp = lane >> 4;
    const int r0   = blockIdx.x * BTILE;

    // per-wave fragment-packed weight bases (include lane*8)
    const unsigned short* tb1 = ws + OW1 + wid * (9 * 4 * 512)  + (lane << 3);
    const unsigned short* tb2 = ws + OW2 + wid * (14 * 4 * 512) + (lane << 3);
    const unsigned short* tf1 = ws + OF1 + wid * (9 * 512)      + (lane << 3);
    const unsigned short* tf2 = ws + OF2 + (wid < 3 ? wid : 0) * (7 * 512) + (lane << 3);

    // ---- prologue ----
    for (int i = tid; i < BTILE * XS;      i += BT) xbuf[i] = 0;
    for (int i = tid; i < 2 * BTILE * HS;  i += BT) h1buf[0][i] = 0;
    for (int i = tid; i < 2 * BTILE * H2S; i += BT) h2cat[0][i] = 0;
    for (int i = tid; i < BTILE * OS;      i += BT) o3buf[i] = 0;
    __syncthreads();
    if (tid < BTILE) {
        const unsigned short ONE = 0x3F80;
        xbuf[tid * XS + 60] = ONE;
        h1buf[0][tid * HS + 208] = ONE;  h1buf[1][tid * HS + 208] = ONE;
        h2cat[0][tid * H2S + 256] = ONE; h2cat[1][tid * H2S + 256] = ONE;
        o3buf[tid * OS + 208] = ONE;
    }
    if (tid < BTILE * 6) {
        int b = tid / 6, m = tid - b * 6;
        xbuf[b * XS + 54 + m] = f2bf(acts[(size_t)(r0 + b) * 6 + m]);                 // state = acts[0]
        xbuf[b * XS + 48 + m] = f2bf(acts[((size_t)1 * BATCH + r0 + b) * 6 + m]);     // action step 0
    }
    for (int i = tid; i < BTILE * 48; i += BT) {
        int b = i / 48, j = i - b * 48;
        unsigned short v = f2bf(tact[(size_t)(r0 + b) * 48 + j]);                      // tact[0]
        xbuf[b * XS + j] = v;
        h2cat[0][b * H2S + 208 + j] = v;
    }
    __syncthreads();

    float c1[2][4], c2[2][4];
#pragma unroll
    for (int m = 0; m < 2; ++m)
#pragma unroll
    for (int r = 0; r < 4; ++r) { c1[m][r] = 0.f; c2[m][r] = 0.f; }

    // 12-slot register FIFO; prime with loads 0..10 (11 in flight, always)
    bf16x8 wq[12];
    if (wid < 13) {
#pragma unroll
        for (int i = 0; i < 11; ++i) WQI(i, i);
    }

#pragma unroll 1
    for (int idx = 0; idx < NSTEP; ++idx) {
        const int p = idx & 1;
        unsigned short* h1n = h1buf[p];
        unsigned short* h1o = h1buf[p ^ 1];
        unsigned short* h2n = h2cat[p];
        unsigned short* h2o = h2cat[p ^ 1];

        // ---- P1: LSTM1 (x | h1_old) -> h1_new ; consume loads 0..35 ----
        if (wid < 13) {
            const int n = wid * 16 + lrow;
            f32x4 acc[4][2];
#pragma unroll
            for (int g = 0; g < 4; ++g) { acc[g][0] = {0.f,0.f,0.f,0.f}; acc[g][1] = {0.f,0.f,0.f,0.f}; }
#pragma unroll
            for (int kc = 0; kc < 9; ++kc) {
                const int koff = kc * 32 + lgrp * 8;
                bf16x8 a0, a1;
                if (kc < 2) {
                    a0 = *(const bf16x8*)(xbuf + lrow * XS + koff);
                    a1 = *(const bf16x8*)(xbuf + (lrow + 16) * XS + koff);
                } else {
                    a0 = *(const bf16x8*)(h1o + lrow * HS + koff - 64);
                    a1 = *(const bf16x8*)(h1o + (lrow + 16) * HS + koff - 64);
                }
#pragma unroll
                for (int g = 0; g < 4; ++g) {
                    const int i = 4 * kc + g;
                    WQI(i + 11, i + 11);
                    VMWAIT;
                    acc[g][0] = __builtin_amdgcn_mfma_f32_16x16x32_bf16(a0, wq[i % 12], acc[g][0], 0, 0, 0);
                    acc[g][1] = __builtin_amdgcn_mfma_f32_16x16x32_bf16(a1, wq[i % 12], acc[g][1], 0, 0, 0);
                }
            }
#pragma unroll
            for (int m = 0; m < 2; ++m)
#pragma unroll
            for (int r = 0; r < 4; ++r) {
                float c = sigf(acc[1][m][r]) * c1[m][r] + sigf(acc[0][m][r]) * tanh_(acc[2][m][r]);
                c1[m][r] = c;
                h1n[(m * 16 + lgrp * 4 + r) * HS + n] = f2bf(sigf(acc[3][m][r]) * tanh_(c));
            }
        }
        PHASE_BARRIER;

        // ---- P2: LSTM2 (h1_new | h2_old) -> h2_new ; consume 36..91 ----
        // waves 13..15: stage next-step inputs (no weight pipeline to pollute)
        if (wid < 13) {
            f32x4 acc[4][2];
#pragma unroll
            for (int g = 0; g < 4; ++g) { acc[g][0] = {0.f,0.f,0.f,0.f}; acc[g][1] = {0.f,0.f,0.f,0.f}; }
#pragma unroll
            for (int kc = 0; kc < 14; ++kc) {
                const int koff = kc * 32 + lgrp * 8;
                bf16x8 a0, a1;
                if (kc < 7) {
                    a0 = *(const bf16x8*)(h1n + lrow * HS + koff);
                    a1 = *(const bf16x8*)(h1n + (lrow + 16) * HS + koff);
                } else {
                    a0 = *(const bf16x8*)(h2o + lrow * H2S + koff - 224);
                    a1 = *(const bf16x8*)(h2o + (lrow + 16) * H2S + koff - 224);
                }
#pragma unroll
                for (int g = 0; g < 4; ++g) {
                    const int i = 36 + 4 * kc + g;
                    WQI(i + 11, i + 11);
                    VMWAIT;
                    acc[g][0] = __builtin_amdgcn_mfma_f32_16x16x32_bf16(a0, wq[i % 12], acc[g][0], 0, 0, 0);
                    acc[g][1] = __builtin_amdgcn_mfma_f32_16x16x32_bf16(a1, wq[i % 12], acc[g][1], 0, 0, 0);
                }
            }
            const int n = wid * 16 + lrow;
#pragma unroll
            for (int m = 0; m < 2; ++m)
#pragma unroll
            for (int r = 0; r < 4; ++r) {
                float c = sigf(acc[1][m][r]) * c2[m][r] + sigf(acc[0][m][r]) * tanh_(acc[2][m][r]);
                c2[m][r] = c;
                h2n[(m * 16 + lgrp * 4 + r) * H2S + n] = f2bf(sigf(acc[3][m][r]) * tanh_(c));
            }
        } else if (idx < NSTEP - 1) {
            const int t3 = tid - 13 * 64;    // 0..191
            {   // action for step idx+1 = acts[idx+2]
                int b = t3 / 6, m = t3 - b * 6;
                xbuf[b * XS + 48 + m] = f2bf(acts[((size_t)(idx + 2) * BATCH + r0 + b) * 6 + m]);
            }
            if (idx < 9) {                   // ground-truth tactile for step idx+1
#pragma unroll
                for (int rr = 0; rr < 8; ++rr) {
                    int e = t3 + rr * 192;
                    int b = e / 48, j = e - b * 48;
                    unsigned short v = f2bf(tact[((size_t)(idx + 1) * BATCH + r0 + b) * 48 + j]);
                    xbuf[b * XS + j] = v;
                    h2cat[p ^ 1][b * H2S + 208 + j] = v;   // overlap cols hit zero weights in P2
                }
            }
        }
        PHASE_BARRIER;

        // ---- P3: FC1 (h2_new|inp|1) -> o3 ; consume 92..100 ----
        if (wid < 13) {
            const int n = wid * 16 + lrow;
            f32x4 a0c = {0.f,0.f,0.f,0.f}, a1c = {0.f,0.f,0.f,0.f};
#pragma unroll
            for (int kc = 0; kc < 9; ++kc) {
                const int koff = kc * 32 + lgrp * 8;
                bf16x8 a0 = *(const bf16x8*)(h2n + lrow * H2S + koff);
                bf16x8 a1 = *(const bf16x8*)(h2n + (lrow + 16) * H2S + koff);
                WQI(103 + kc, 103 + kc);
                VMWAIT;
                a0c = __builtin_amdgcn_mfma_f32_16x16x32_bf16(a0, wq[(92 + kc) % 12], a0c, 0, 0, 0);
                a1c = __builtin_amdgcn_mfma_f32_16x16x32_bf16(a1, wq[(92 + kc) % 12], a1c, 0, 0, 0);
            }
#pragma unroll
            for (int r = 0; r < 4; ++r) {
                o3buf[(lgrp * 4 + r) * OS + n]      = f2bf(tanh_(a0c[r]));
                o3buf[(16 + lgrp * 4 + r) * OS + n] = f2bf(tanh_(a1c[r]));
            }
        }
        PHASE_BARRIER;

        // ---- P4: FC2 (o3|1) -> out4 ; consume 101..107 (all 13 waves keep the
        // pipeline uniform; only wid<3 use results) ----
        if (wid < 13) {
            f32x4 a0c = {0.f,0.f,0.f,0.f}, a1c = {0.f,0.f,0.f,0.f};
#pragma unroll
            for (int kc = 0; kc < 7; ++kc) {
                const int koff = kc * 32 + lgrp * 8;
                bf16x8 a0 = *(const bf16x8*)(o3buf + lrow * OS + koff);
                bf16x8 a1 = *(const bf16x8*)(o3buf + (lrow + 16) * OS + koff);
                WQI(112 + kc, 112 + kc);
                VMWAIT;
                a0c = __builtin_amdgcn_mfma_f32_16x16x32_bf16(a0, wq[(101 + kc) % 12], a0c, 0, 0, 0);
                a1c = __builtin_amdgcn_mfma_f32_16x16x32_bf16(a1, wq[(101 + kc) % 12], a1c, 0, 0, 0);
            }
            if (wid < 3 && idx >= 9) {
                const int n = wid * 16 + lrow;   // 0..47
#pragma unroll
                for (int m = 0; m < 2; ++m)
#pragma unroll
                for (int r = 0; r < 4; ++r) {
                    const int row = m * 16 + lgrp * 4 + r;
                    float o4 = tanh_(m == 0 ? a0c[r] : a1c[r]);
                    out[((size_t)(idx - 9) * BATCH + r0 + row) * 48 + n] = o4;
                    unsigned short v = f2bf(o4);
                    xbuf[row * XS + n] = v;                 // next-step LSTM input
                    h2cat[p ^ 1][row * H2S + 208 + n] = v;  // next-step FC1 concat input
                }
            }
        }
        PHASE_BARRIER;
    }
}

extern "C" void kernel_launch(void* const* d_in, const int* in_sizes, int n_in,
                              void* d_out, int out_size, void* d_ws, size_t ws_size,
                              hipStream_t stream) {
    (void)in_sizes; (void)n_in; (void)out_size; (void)ws_size;
    const float* tact = (const float*)d_in[0];
    const float* acts = (const float*)d_in[1];
    const float* wih1 = (const float*)d_in[2];
    const float* whh1 = (const float*)d_in[3];
    const float* bih1 = (const float*)d_in[4];
    const float* bhh1 = (const float*)d_in[5];
    const float* wih2 = (const float*)d_in[6];
    const float* whh2 = (const float*)d_in[7];
    const float* bih2 = (const float*)d_in[8];
    const float* bhh2 = (const float*)d_in[9];
    const float* fc1w = (const float*)d_in[10];
    const float* fc1b = (const float*)d_in[11];
    const float* fc2w = (const float*)d_in[12];
    const float* fc2b = (const float*)d_in[13];
    unsigned short* ws = (unsigned short*)d_ws;
    float* outp = (float*)d_out;

    actp_prep<<<(WTOT + 255) / 256, 256, 0, stream>>>(wih1, whh1, bih1, bhh1,
                                                      wih2, whh2, bih2, bhh2,
                                                      fc1w, fc1b, fc2w, fc2b, ws);
    actp_main<<<BATCH / BTILE, BT, 0, stream>>>(tact, acts, ws, outp);
}

// Round 7
// 1549.122 us; speedup vs baseline: 1.2405x; 1.2405x over previous
//
#include <hip/hip_runtime.h>

#define BATCH 8192
#define NSTEP 29
#define BTILE 32
#define BT    1024         // 16 waves: 13 compute (N-tiles), 3 input-staging
#define XS    72           // x: [0,48)=tactile/out4, [48,54)=act, [54,60)=state, [60]=1
#define HS    232          // h1: [0,200)=h, [208]=1 (W2 bias col)
#define H2S   264          // h2cat: [0,200)=h2, [200,248)=inp, [248]=1
#define OS    232          // o3: [0,200)=o3, [208]=1 (FC2 bias col)

#define NFRAG 108          // per-wave frags per step: P1 36 | P2 56 | P3 8 | P4 7 + 1 dummy
#define RING  6            // LDS ring depth (frags); 108 % 6 == 0
#define WTOT  (13 * NFRAG * 512)   // ws elems (bf16 as ushort)

typedef __bf16 bf16x8 __attribute__((ext_vector_type(8)));
typedef float  f32x4  __attribute__((ext_vector_type(4)));

#define MFMA(a, b, c) __builtin_amdgcn_mfma_f32_16x16x32_bf16(a, b, c, 0, 0, 0)

__device__ __forceinline__ unsigned short f2bf(float f) {
    union { float f; unsigned u; } v; v.f = f;
    unsigned r = v.u + 0x7fffu + ((v.u >> 16) & 1u);
    return (unsigned short)(r >> 16);
}
__device__ __forceinline__ float sigf(float x) {
    return __builtin_amdgcn_rcpf(1.0f + __expf(-x));
}
__device__ __forceinline__ float tanhf_(float x) {
    // NaN-free: exp->inf => 1-0=1 ; exp->0 => 1-2=-1
    return 1.0f - 2.0f * __builtin_amdgcn_rcpf(__expf(2.0f * x) + 1.0f);
}

__device__ __forceinline__ void glds16(const unsigned short* g, unsigned short* l) {
    __builtin_amdgcn_global_load_lds(
        (const __attribute__((address_space(1))) unsigned int*)g,
        (__attribute__((address_space(3))) unsigned int*)l, 16, 0, 0);
}

#define PHASE_BARRIER do { \
    asm volatile("s_waitcnt lgkmcnt(0)" ::: "memory"); \
    __builtin_amdgcn_s_barrier(); \
} while (0)

// ---- prep: per-wave contiguous, consumption-ordered frag stream ----
// frag fi: [0,36) W1 (kc=fi/4,g=fi%4; K: x[0,60)|bias@60|h1[64,288))
//          [36,92) W2 (K: h1[0,200)|bias@208|h2[224,424))
//          [92,100) FC1 (K: fc1w natural [0,248)|bias@248)
//          [100,107) FC2 (K: fc2w[0,200)|bias@208) ; 107 dummy=0
__global__ void actp_prep(const float* __restrict__ wih1, const float* __restrict__ whh1,
                          const float* __restrict__ bih1, const float* __restrict__ bhh1,
                          const float* __restrict__ wih2, const float* __restrict__ whh2,
                          const float* __restrict__ bih2, const float* __restrict__ bhh2,
                          const float* __restrict__ fc1w, const float* __restrict__ fc1b,
                          const float* __restrict__ fc2w, const float* __restrict__ fc2b,
                          unsigned short* __restrict__ ws) {
    int i = blockIdx.x * 256 + threadIdx.x;
    if (i >= WTOT) return;
    int wid = i / (NFRAG * 512);
    int r   = i % (NFRAG * 512);
    int fi  = r >> 9;
    int le  = r & 511;
    int lane = le >> 3, e = le & 7;
    int lrow = lane & 15, lgrp = lane >> 4;
    float v = 0.f;
    if (fi < 36) {
        int kc = fi >> 2, g = fi & 3;
        int n = wid * 16 + lrow, k = kc * 32 + lgrp * 8 + e;
        if (n < 200) {
            int o = g * 200 + n;
            if (k < 60)                   v = wih1[o * 60 + k];
            else if (k == 60)             v = bih1[o] + bhh1[o];
            else if (k >= 64 && k < 264)  v = whh1[o * 200 + (k - 64)];
        }
    } else if (fi < 92) {
        int j = fi - 36; int kc = j >> 2, g = j & 3;
        int n = wid * 16 + lrow, k = kc * 32 + lgrp * 8 + e;
        if (n < 200) {
            int o = g * 200 + n;
            if (k < 200)                   v = wih2[o * 200 + k];
            else if (k == 208)             v = bih2[o] + bhh2[o];
            else if (k >= 224 && k < 424)  v = whh2[o * 200 + (k - 224)];
        }
    } else if (fi < 100) {
        int n = wid * 16 + lrow, k = (fi - 92) * 32 + lgrp * 8 + e;
        if (n < 200) {
            if (k < 248)       v = fc1w[n * 248 + k];
            else if (k == 248) v = fc1b[n];
        }
    } else if (fi < 107) {
        int n = (wid % 3) * 16 + lrow, k = (fi - 100) * 32 + lgrp * 8 + e;
        if (k < 200)       v = fc2w[n * 200 + k];
        else if (k == 208) v = fc2b[n];
    }
    ws[i] = (v == 0.f) ? (unsigned short)0 : f2bf(v);
}

// ---- ring pipeline bodies (F = absolute in-step frag index, compile-time after unroll) ----
// invariant at group entry: issued_through = first_frag + 5
__device__ __forceinline__ void grp4(int F,
    const unsigned short* a0p, const unsigned short* a1p,
    const unsigned short* ringrd, const unsigned short* wsrc, unsigned short* ringdst,
    f32x4 (&acc)[4][2])
{
    asm volatile("s_waitcnt vmcnt(2)" ::: "memory");
    __builtin_amdgcn_sched_barrier(0);
    bf16x8 a0 = *(const bf16x8*)a0p;
    bf16x8 a1 = *(const bf16x8*)a1p;
    bf16x8 b0 = *(const bf16x8*)(ringrd + ((F + 0) % RING) * 512);
    bf16x8 b1 = *(const bf16x8*)(ringrd + ((F + 1) % RING) * 512);
    bf16x8 b2 = *(const bf16x8*)(ringrd + ((F + 2) % RING) * 512);
    bf16x8 b3 = *(const bf16x8*)(ringrd + ((F + 3) % RING) * 512);
    asm volatile("s_waitcnt lgkmcnt(0)" ::: "memory");
    __builtin_amdgcn_sched_barrier(0);
    glds16(wsrc + ((F + 6) % NFRAG) * 512, ringdst + ((F + 0) % RING) * 512);
    glds16(wsrc + ((F + 7) % NFRAG) * 512, ringdst + ((F + 1) % RING) * 512);
    glds16(wsrc + ((F + 8) % NFRAG) * 512, ringdst + ((F + 2) % RING) * 512);
    glds16(wsrc + ((F + 9) % NFRAG) * 512, ringdst + ((F + 3) % RING) * 512);
    __builtin_amdgcn_sched_barrier(0);
    acc[0][0] = MFMA(a0, b0, acc[0][0]); acc[0][1] = MFMA(a1, b0, acc[0][1]);
    acc[1][0] = MFMA(a0, b1, acc[1][0]); acc[1][1] = MFMA(a1, b1, acc[1][1]);
    acc[2][0] = MFMA(a0, b2, acc[2][0]); acc[2][1] = MFMA(a1, b2, acc[2][1]);
    acc[3][0] = MFMA(a0, b3, acc[3][0]); acc[3][1] = MFMA(a1, b3, acc[3][1]);
}

__device__ __forceinline__ void grp1(int F,
    const unsigned short* a0p, const unsigned short* a1p,
    const unsigned short* ringrd, const unsigned short* wsrc, unsigned short* ringdst,
    f32x4 &c0, f32x4 &c1)
{
    asm volatile("s_waitcnt vmcnt(4)" ::: "memory");
    __builtin_amdgcn_sched_barrier(0);
    bf16x8 a0 = *(const bf16x8*)a0p;
    bf16x8 a1 = *(const bf16x8*)a1p;
    bf16x8 b  = *(const bf16x8*)(ringrd + (F % RING) * 512);
    asm volatile("s_waitcnt lgkmcnt(0)" ::: "memory");
    __builtin_amdgcn_sched_barrier(0);
    glds16(wsrc + ((F + 6) % NFRAG) * 512, ringdst + (F % RING) * 512);
    __builtin_amdgcn_sched_barrier(0);
    c0 = MFMA(a0, b, c0);
    c1 = MFMA(a1, b, c1);
}

__global__ __launch_bounds__(BT, 4) void actp_main(
    const float* __restrict__ tact, const float* __restrict__ acts,
    const unsigned short* __restrict__ ws, float* __restrict__ out)
{
    __shared__ alignas(16) unsigned short xbuf[BTILE * XS];
    __shared__ alignas(16) unsigned short h1buf[2][BTILE * HS];
    __shared__ alignas(16) unsigned short h2cat[2][BTILE * H2S];
    __shared__ alignas(16) unsigned short o3buf[BTILE * OS];
    __shared__ alignas(16) unsigned short wring[13 * RING * 512];   // 79872 B

    const int tid  = threadIdx.x;
    const int lane = tid & 63;
    const int wid  = tid >> 6;      // 0..15
    const int lrow = lane & 15;
    const int lgrp = lane >> 4;
    const int r0   = blockIdx.x * BTILE;

    const int wslot = (wid < 13) ? wid : 0;
    const unsigned short* wsrc   = ws + (size_t)wslot * NFRAG * 512 + (lane << 3); // per-lane
    const unsigned short* ringrd = wring + wslot * (RING * 512) + (lane << 3);     // per-lane
    unsigned short*       ringdst = wring + wslot * (RING * 512);                  // wave-uniform

    // ---- prologue ----
    for (int i = tid; i < BTILE * XS;      i += BT) xbuf[i] = 0;
    for (int i = tid; i < 2 * BTILE * HS;  i += BT) h1buf[0][i] = 0;
    for (int i = tid; i < 2 * BTILE * H2S; i += BT) h2cat[0][i] = 0;
    for (int i = tid; i < BTILE * OS;      i += BT) o3buf[i] = 0;
    __syncthreads();
    if (tid < BTILE) {
        const unsigned short ONE = 0x3F80;
        xbuf[tid * XS + 60] = ONE;
        h1buf[0][tid * HS + 208] = ONE;  h1buf[1][tid * HS + 208] = ONE;
        h2cat[0][tid * H2S + 248] = ONE; h2cat[1][tid * H2S + 248] = ONE;
        o3buf[tid * OS + 208] = ONE;
    }
    if (tid < BTILE * 6) {
        int b = tid / 6, m = tid - b * 6;
        xbuf[b * XS + 54 + m] = f2bf(acts[(size_t)(r0 + b) * 6 + m]);               // state = acts[0]
        xbuf[b * XS + 48 + m] = f2bf(acts[((size_t)1 * BATCH + r0 + b) * 6 + m]);   // action step 0
    }
    for (int i = tid; i < BTILE * 48; i += BT) {
        int b = i / 48, j = i - b * 48;
        unsigned short v = f2bf(tact[(size_t)(r0 + b) * 48 + j]);                    // tact[0]
        xbuf[b * XS + j] = v;
        h2cat[0][b * H2S + 200 + j] = v;
    }
    __syncthreads();

    float c1[2][4], c2[2][4];
#pragma unroll
    for (int m = 0; m < 2; ++m)
#pragma unroll
    for (int r = 0; r < 4; ++r) { c1[m][r] = 0.f; c2[m][r] = 0.f; }

    // prime ring: issue frags 0..5 (invariant: issued_through = 5)
    if (wid < 13) {
#pragma unroll
        for (int f = 0; f < RING; ++f)
            glds16(wsrc + f * 512, ringdst + f * 512);
        __builtin_amdgcn_sched_barrier(0);
    }

    // per-phase A bases (per-lane, elems)
    const unsigned short* ax  = xbuf + lrow * XS + lgrp * 8;
    const unsigned short* ax1 = xbuf + (lrow + 16) * XS + lgrp * 8;

#pragma unroll 1
    for (int idx = 0; idx < NSTEP; ++idx) {
        const int p = idx & 1;
        unsigned short* h1n = h1buf[p];
        unsigned short* h1o = h1buf[p ^ 1];
        unsigned short* h2n = h2cat[p];
        unsigned short* h2o = h2cat[p ^ 1];

        // ---- P1: LSTM1 (x | h1_old) -> h1_new ; frags 0..35 ----
        if (wid < 13) {
            const unsigned short* ah  = h1o + lrow * HS + lgrp * 8;
            const unsigned short* ah1 = h1o + (lrow + 16) * HS + lgrp * 8;
            f32x4 acc[4][2];
#pragma unroll
            for (int g = 0; g < 4; ++g) { acc[g][0] = {0.f,0.f,0.f,0.f}; acc[g][1] = {0.f,0.f,0.f,0.f}; }
#pragma unroll
            for (int kc = 0; kc < 9; ++kc) {
                const unsigned short* a0p = (kc < 2) ? (ax + kc * 32)  : (ah + kc * 32 - 64);
                const unsigned short* a1p = (kc < 2) ? (ax1 + kc * 32) : (ah1 + kc * 32 - 64);
                grp4(4 * kc, a0p, a1p, ringrd, wsrc, ringdst, acc);
            }
            const int n = wid * 16 + lrow;
#pragma unroll
            for (int m = 0; m < 2; ++m)
#pragma unroll
            for (int r = 0; r < 4; ++r) {
                float c = sigf(acc[1][m][r]) * c1[m][r] + sigf(acc[0][m][r]) * tanhf_(acc[2][m][r]);
                c1[m][r] = c;
                h1n[(m * 16 + lgrp * 4 + r) * HS + n] = f2bf(sigf(acc[3][m][r]) * tanhf_(c));
            }
        }
        PHASE_BARRIER;

        // ---- P2: LSTM2 (h1_new | h2_old) -> h2_new ; frags 36..91 ----
        if (wid < 13) {
            const unsigned short* ah  = h1n + lrow * HS + lgrp * 8;
            const unsigned short* ah1 = h1n + (lrow + 16) * HS + lgrp * 8;
            const unsigned short* a2  = h2o + lrow * H2S + lgrp * 8;
            const unsigned short* a21 = h2o + (lrow + 16) * H2S + lgrp * 8;
            f32x4 acc[4][2];
#pragma unroll
            for (int g = 0; g < 4; ++g) { acc[g][0] = {0.f,0.f,0.f,0.f}; acc[g][1] = {0.f,0.f,0.f,0.f}; }
#pragma unroll
            for (int kc = 0; kc < 14; ++kc) {
                const unsigned short* a0p = (kc < 7) ? (ah + kc * 32)  : (a2 + kc * 32 - 224);
                const unsigned short* a1p = (kc < 7) ? (ah1 + kc * 32) : (a21 + kc * 32 - 224);
                grp4(36 + 4 * kc, a0p, a1p, ringrd, wsrc, ringdst, acc);
            }
            const int n = wid * 16 + lrow;
#pragma unroll
            for (int m = 0; m < 2; ++m)
#pragma unroll
            for (int r = 0; r < 4; ++r) {
                float c = sigf(acc[1][m][r]) * c2[m][r] + sigf(acc[0][m][r]) * tanhf_(acc[2][m][r]);
                c2[m][r] = c;
                if (n < 200)   // protect inp columns [200,248)
                    h2n[(m * 16 + lgrp * 4 + r) * H2S + n] = f2bf(sigf(acc[3][m][r]) * tanhf_(c));
            }
        } else if (idx < NSTEP - 1) {
            const int t3 = tid - 13 * 64;    // 0..191
            {   // action for step idx+1 = acts[idx+2]
                int b = t3 / 6, m = t3 - b * 6;
                xbuf[b * XS + 48 + m] = f2bf(acts[((size_t)(idx + 2) * BATCH + r0 + b) * 6 + m]);
            }
            if (idx < 9) {                   // ground-truth tactile for step idx+1
#pragma unroll
                for (int rr = 0; rr < 8; ++rr) {
                    int e = t3 + rr * 192;
                    int b = e / 48, j = e - b * 48;
                    unsigned short v = f2bf(tact[((size_t)(idx + 1) * BATCH + r0 + b) * 48 + j]);
                    xbuf[b * XS + j] = v;
                    h2cat[p ^ 1][b * H2S + 200 + j] = v;   // overlap cols hit zero W2 weights
                }
            }
        }
        PHASE_BARRIER;

        // ---- P3: FC1 (h2_new|inp|1) -> o3 ; frags 92..99 ----
        if (wid < 13) {
            const unsigned short* a2  = h2n + lrow * H2S + lgrp * 8;
            const unsigned short* a21 = h2n + (lrow + 16) * H2S + lgrp * 8;
            f32x4 a0c = {0.f,0.f,0.f,0.f}, a1c = {0.f,0.f,0.f,0.f};
#pragma unroll
            for (int kc = 0; kc < 8; ++kc)
                grp1(92 + kc, a2 + kc * 32, a21 + kc * 32, ringrd, wsrc, ringdst, a0c, a1c);
            const int n = wid * 16 + lrow;
#pragma unroll
            for (int r = 0; r < 4; ++r) {
                o3buf[(lgrp * 4 + r) * OS + n]      = f2bf(tanhf_(a0c[r]));
                o3buf[(16 + lgrp * 4 + r) * OS + n] = f2bf(tanhf_(a1c[r]));
            }
        }
        PHASE_BARRIER;

        // ---- P4: FC2 (o3|1) -> out4 ; frags 100..106 + dummy 107 ----
        if (wid < 13) {
            const unsigned short* ao  = o3buf + lrow * OS + lgrp * 8;
            const unsigned short* ao1 = o3buf + (lrow + 16) * OS + lgrp * 8;
            f32x4 a0c = {0.f,0.f,0.f,0.f}, a1c = {0.f,0.f,0.f,0.f};
#pragma unroll
            for (int kc = 0; kc < 7; ++kc)
                grp1(100 + kc, ao + kc * 32, ao1 + kc * 32, ringrd, wsrc, ringdst, a0c, a1c);
            // dummy frag 107: keep ring/vmcnt invariant (no read, no MFMA)
            asm volatile("s_waitcnt vmcnt(4)" ::: "memory");
            __builtin_amdgcn_sched_barrier(0);
            glds16(wsrc + ((107 + 6) % NFRAG) * 512, ringdst + (107 % RING) * 512);
            __builtin_amdgcn_sched_barrier(0);

            if (wid < 3 && idx >= 9) {
                const int n = wid * 16 + lrow;   // 0..47
#pragma unroll
                for (int m = 0; m < 2; ++m)
#pragma unroll
                for (int r = 0; r < 4; ++r) {
                    const int row = m * 16 + lgrp * 4 + r;
                    float o4 = tanhf_(m == 0 ? a0c[r] : a1c[r]);
                    out[((size_t)(idx - 9) * BATCH + r0 + row) * 48 + n] = o4;
                    unsigned short v = f2bf(o4);
                    xbuf[row * XS + n] = v;                 // next-step LSTM input
                    h2cat[p ^ 1][row * H2S + 200 + n] = v;  // next-step FC1 concat input
                }
            }
        }
        PHASE_BARRIER;
    }
}

extern "C" void kernel_launch(void* const* d_in, const int* in_sizes, int n_in,
                              void* d_out, int out_size, void* d_ws, size_t ws_size,
                              hipStream_t stream) {
    (void)in_sizes; (void)n_in; (void)out_size; (void)ws_size;
    const float* tact = (const float*)d_in[0];
    const float* acts = (const float*)d_in[1];
    const float* wih1 = (const float*)d_in[2];
    const float* whh1 = (const float*)d_in[3];
    const float* bih1 = (const float*)d_in[4];
    const float* bhh1 = (const float*)d_in[5];
    const float* wih2 = (const float*)d_in[6];
    const float* whh2 = (const float*)d_in[7];
    const float* bih2 = (const float*)d_in[8];
    const float* bhh2 = (const float*)d_in[9];
    const float* fc1w = (const float*)d_in[10];
    const float* fc1b = (const float*)d_in[11];
    const float* fc2w = (const float*)d_in[12];
    const float* fc2b = (const float*)d_in[13];
    unsigned short* ws = (unsigned short*)d_ws;
    float* outp = (float*)d_out;

    actp_prep<<<(WTOT + 255) / 256, 256, 0, stream>>>(wih1, whh1, bih1, bhh1,
                                                      wih2, whh2, bih2, bhh2,
                                                      fc1w, fc1b, fc2w, fc2b, ws);
    actp_main<<<BATCH / BTILE, BT, 0, stream>>>(tact, acts, ws, outp);
}